// Round 14
// baseline (3409.822 us; speedup 1.0000x reference)
//
#include <hip/hip_runtime.h>
#include <hip/hip_bf16.h>

// LSTM T=4096, B=16, I=64, H=256 (4H=1024 gate rows), O=1.
//
// R14 = R13 (2985us, absmax 2e-3) + independent MFMA accumulators.
// R13 step = 1749 cyc vs 1306-cyc i8-MFMA issue floor; MfmaUtil/active 58%
// suggests issue stalls from the 4-deep dependent accumulate chains when
// waves align. Now: 16 independent accumulators (gate x chunk, C=0), then
// 3 scalar int adds per gate on reg0 only (D rows identical -> only reg0
// consumed). +48 VGPRs (~112 total, still 4 waves/SIMD at 128-cap).
// Everything else identical to R13 (verified): i8 16x16x64, per-gate-row
// symmetric quant, h int8 LDS identity layout, magic-number RNE h-quantize,
// ONE barrier/step, xg fp16 [t][b][u*4+g] prefetched via pointer.

typedef _Float16 f16x2 __attribute__((ext_vector_type(2)));
typedef _Float16 f16x4 __attribute__((ext_vector_type(4)));
typedef int      i32x4 __attribute__((ext_vector_type(4)));

#define T_STEPS 4096
#define BATCH   16
#define IN      64
#define HID     256
#define G4      1024

__device__ __forceinline__ float fdot2(f16x2 a, f16x2 b, float c) {
#if __has_builtin(__builtin_amdgcn_fdot2)
    return __builtin_amdgcn_fdot2(a, b, c, false);
#else
    return c + (float)a.x * (float)b.x + (float)a.y * (float)b.y;
#endif
}

__device__ __forceinline__ float fast_rcp(float x) {
#if __has_builtin(__builtin_amdgcn_rcpf)
    return __builtin_amdgcn_rcpf(x);
#else
    return 1.0f / x;
#endif
}

__device__ __forceinline__ float sigf(float x) {
    return fast_rcp(1.0f + __expf(-x));
}
__device__ __forceinline__ float tanh_fast(float x) {
    return 2.0f * sigf(2.0f * x) - 1.0f;
}

// ---------------- Kernel A: x_gates precompute (transposed store) ----------
__global__ __launch_bounds__(256) void xg_precompute(
    const float* __restrict__ x, const float* __restrict__ W_ih,
    const float* __restrict__ b_ih, const float* __restrict__ b_hh,
    _Float16* __restrict__ xg)
{
    const int b   = blockIdx.x;
    const int t0  = blockIdx.y * 128;
    const int tid = threadIdx.x;

    __shared__ __align__(16) f16x2 xs2[IN / 2];

    f16x2 wih[4][32];
    float bias[4];
    const float2* W2 = (const float2*)W_ih;
    #pragma unroll
    for (int g = 0; g < 4; ++g) {
        const int r = tid + g * 256;
        #pragma unroll
        for (int m = 0; m < 32; ++m) {
            float2 v = W2[r * 32 + m];
            wih[g][m] = f16x2{(_Float16)v.x, (_Float16)v.y};
        }
        bias[g] = b_ih[r] + b_hh[r];
    }

    for (int tt = 0; tt < 128; ++tt) {
        const int t = t0 + tt;
        if (tid < 32) {
            float2 v = ((const float2*)x)[(t * BATCH + b) * 32 + tid];
            xs2[tid] = f16x2{(_Float16)v.x, (_Float16)v.y};
        }
        __syncthreads();
        float acc[4] = {bias[0], bias[1], bias[2], bias[3]};
        #pragma unroll
        for (int m = 0; m < 32; ++m) {
            f16x2 xv = xs2[m];
            #pragma unroll
            for (int g = 0; g < 4; ++g) acc[g] = fdot2(wih[g][m], xv, acc[g]);
        }
        f16x4 v4 = f16x4{(_Float16)acc[0], (_Float16)acc[1],
                         (_Float16)acc[2], (_Float16)acc[3]};
        ((f16x4*)xg)[(t * BATCH + b) * 256 + tid] = v4;
        __syncthreads();
    }
}

// ---------------- Kernel B: i8-MFMA persistent recurrence ----------------
__global__ __launch_bounds__(1024, 4) void lstm_mfma(
    const float* __restrict__ W_hh,  const float* __restrict__ W_lin,
    const float* __restrict__ b_lin, const float* __restrict__ h0,
    const float* __restrict__ c0,    const _Float16* __restrict__ xg,
    float* __restrict__ out)
{
    const int b   = blockIdx.x;
    const int tid = threadIdx.x;
    const int w   = tid >> 6;     // wave 0..15
    const int l   = tid & 63;     // lane
    const int col = l & 15;       // MFMA col for this lane
    const int g4  = l >> 4;       // k lane-group 0..3

    __shared__ __align__(16) signed char hs[2][256];  // h int8, identity layout
    __shared__ float esh[256];

    const int u = w * 16 + col;   // unit this lane covers

    // ---- one-time: per-gate-row max, then W_hh -> int8 B-fragments ----
    const float4* Wh4 = (const float4*)W_hh;          // row stride 64 float4
    float qs[4], ksc[4];
    {
        float rm[4];
        #pragma unroll
        for (int g = 0; g < 4; ++g) {
            const int row = g * 256 + u;
            float m = 0.0f;
            #pragma unroll
            for (int c = 0; c < 4; ++c) {
                #pragma unroll
                for (int d = 0; d < 4; ++d) {
                    float4 v = Wh4[row * 64 + 16 * c + 4 * g4 + d];
                    m = fmaxf(m, fmaxf(fmaxf(fabsf(v.x), fabsf(v.y)),
                                       fmaxf(fabsf(v.z), fabsf(v.w))));
                }
            }
            rm[g] = m;
        }
        #pragma unroll
        for (int g = 0; g < 4; ++g) {                  // max across g4 groups
            rm[g] = fmaxf(rm[g], __shfl_xor(rm[g], 16, 64));
            rm[g] = fmaxf(rm[g], __shfl_xor(rm[g], 32, 64));
            rm[g] = fmaxf(rm[g], 1e-20f);
            qs[g]  = 127.0f / rm[g];
            ksc[g] = rm[g] * (1.0f / 16129.0f);        // rm/127^2
        }
    }
    i32x4 wf[4][4];
    #pragma unroll
    for (int g = 0; g < 4; ++g) {
        const int row = g * 256 + u;
        #pragma unroll
        for (int c = 0; c < 4; ++c) {
            union { int i[4]; i32x4 v; } uu;
            #pragma unroll
            for (int d = 0; d < 4; ++d) {
                float4 v = Wh4[row * 64 + 16 * c + 4 * g4 + d];
                int b0 = (int)rintf(v.x * qs[g]) & 255;
                int b1 = (int)rintf(v.y * qs[g]) & 255;
                int b2 = (int)rintf(v.z * qs[g]) & 255;
                int b3 = (int)rintf(v.w * qs[g]) & 255;
                uu.i[d] = b0 | (b1 << 8) | (b2 << 16) | (b3 << 24);
            }
            wf[g][c] = uu.v;
        }
    }

    // ---- state (lane l<16 owns unit u's write) ----
    const float MAGIC = 12582912.0f;                   // 1.5 * 2^23
    float cst  = c0[b * HID + u];
    float hval = h0[b * HID + u];
    if (l < 16) {
        union { float f; int i; } m0;
        m0.f = __builtin_fmaf(hval, 127.0f, MAGIC);    // RNE int in low bits
        hs[0][u] = (signed char)(m0.i & 0xff);
    }

    union XU { uint2 i; f16x4 h; };
    const uint2* xp = (const uint2*)xg + b * 256 + u;  // stride BATCH*256/step
    XU xc; xc.i = *xp;
    xp += BATCH * 256;

    for (int t = 0; t < T_STEPS; ++t) {
        __syncthreads();   // h(t) in hs[t&1] visible

        // A fragments: chunk c = bytes [64c + 16*g4, +16) -> 4x b128 broadcast
        const uint4* hsv = (const uint4*)(&hs[t & 1][0]);
        union AU { uint4 q; i32x4 v; } a0, a1, a2, a3;
        a0.q = hsv[g4];
        a1.q = hsv[4 + g4];
        a2.q = hsv[8 + g4];
        a3.q = hsv[12 + g4];

        // prefetch next step's x-gates (pointer-incremented)
        XU xn;
        if (t + 1 < T_STEPS) { xn.i = *xp; xp += BATCH * 256; }
        else                 { xn = xc; }

        // 16 INDEPENDENT accumulators: no MFMA dep chains
        i32x4 p00 = {0,0,0,0}, p01 = {0,0,0,0}, p02 = {0,0,0,0}, p03 = {0,0,0,0};
        i32x4 p10 = {0,0,0,0}, p11 = {0,0,0,0}, p12 = {0,0,0,0}, p13 = {0,0,0,0};
        i32x4 p20 = {0,0,0,0}, p21 = {0,0,0,0}, p22 = {0,0,0,0}, p23 = {0,0,0,0};
        i32x4 p30 = {0,0,0,0}, p31 = {0,0,0,0}, p32 = {0,0,0,0}, p33 = {0,0,0,0};

        p00 = __builtin_amdgcn_mfma_i32_16x16x64_i8(a0.v, wf[0][0], p00, 0, 0, 0);
        p10 = __builtin_amdgcn_mfma_i32_16x16x64_i8(a0.v, wf[1][0], p10, 0, 0, 0);
        p20 = __builtin_amdgcn_mfma_i32_16x16x64_i8(a0.v, wf[2][0], p20, 0, 0, 0);
        p30 = __builtin_amdgcn_mfma_i32_16x16x64_i8(a0.v, wf[3][0], p30, 0, 0, 0);
        p01 = __builtin_amdgcn_mfma_i32_16x16x64_i8(a1.v, wf[0][1], p01, 0, 0, 0);
        p11 = __builtin_amdgcn_mfma_i32_16x16x64_i8(a1.v, wf[1][1], p11, 0, 0, 0);
        p21 = __builtin_amdgcn_mfma_i32_16x16x64_i8(a1.v, wf[2][1], p21, 0, 0, 0);
        p31 = __builtin_amdgcn_mfma_i32_16x16x64_i8(a1.v, wf[3][1], p31, 0, 0, 0);
        p02 = __builtin_amdgcn_mfma_i32_16x16x64_i8(a2.v, wf[0][2], p02, 0, 0, 0);
        p12 = __builtin_amdgcn_mfma_i32_16x16x64_i8(a2.v, wf[1][2], p12, 0, 0, 0);
        p22 = __builtin_amdgcn_mfma_i32_16x16x64_i8(a2.v, wf[2][2], p22, 0, 0, 0);
        p32 = __builtin_amdgcn_mfma_i32_16x16x64_i8(a2.v, wf[3][2], p32, 0, 0, 0);
        p03 = __builtin_amdgcn_mfma_i32_16x16x64_i8(a3.v, wf[0][3], p03, 0, 0, 0);
        p13 = __builtin_amdgcn_mfma_i32_16x16x64_i8(a3.v, wf[1][3], p13, 0, 0, 0);
        p23 = __builtin_amdgcn_mfma_i32_16x16x64_i8(a3.v, wf[2][3], p23, 0, 0, 0);
        p33 = __builtin_amdgcn_mfma_i32_16x16x64_i8(a3.v, wf[3][3], p33, 0, 0, 0);

        // reduce on reg0 only (D rows identical; only reg0 consumed)
        int s0 = (p00[0] + p01[0]) + (p02[0] + p03[0]);
        int s1 = (p10[0] + p11[0]) + (p12[0] + p13[0]);
        int s2 = (p20[0] + p21[0]) + (p22[0] + p23[0]);
        int s3 = (p30[0] + p31[0]) + (p32[0] + p33[0]);

        // All-lane redundant epilogue (issue hides under MFMA shadow).
        float gi = sigf((float)s0 * ksc[0] + (float)xc.h[0]);
        float gf = sigf((float)s1 * ksc[1] + (float)xc.h[1]);
        float gg = tanh_fast((float)s2 * ksc[2] + (float)xc.h[2]);
        float go = sigf((float)s3 * ksc[3] + (float)xc.h[3]);
        cst  = gf * cst + gi * gg;
        hval = go * tanh_fast(cst);
        if (l < 16) {
            union { float f; int i; } mg;
            mg.f = __builtin_fmaf(hval, 127.0f, MAGIC);   // RNE, low byte = i8
            hs[(t + 1) & 1][u] = (signed char)(mg.i & 0xff);
        }
        xc = xn;
    }

    // ---- epilogue: y[b] = sigmoid(h . W_lin + b_lin) ----
    if (l < 16) esh[u] = hval * W_lin[u];
    __syncthreads();
    if (tid == 0) {
        float z = b_lin[0];
        for (int n = 0; n < 256; ++n) z += esh[n];
        out[b] = sigf(z);
    }
}

// ---------------- Fallback (ws too small): R6 dot2 kernel, x streamed ------
#define NTHR 768
#define KC   11
#define REGC 8
#define LDSC 3
#define HPAD 264
#define WT_OFF   0
#define HB_OFF   147456
#define PS_OFF   148512
#define ESH_OFF  156704
#define SMEM_BYTES 157728
typedef _Float16 f16x8 __attribute__((ext_vector_type(8)));

__global__ __launch_bounds__(NTHR, 3) void lstm_fb(
    const float* __restrict__ x,     const float* __restrict__ W_ih,
    const float* __restrict__ W_hh,  const float* __restrict__ b_ih,
    const float* __restrict__ b_hh,  const float* __restrict__ W_lin,
    const float* __restrict__ b_lin, const float* __restrict__ h0,
    const float* __restrict__ c0,    float* __restrict__ out)
{
    const int b   = blockIdx.x;
    const int tid = threadIdx.x;
    const int j   = tid & 255;
    const int s   = tid >> 8;

    extern __shared__ __align__(16) char smem[];
    f16x8*    wt8  = (f16x8*)(smem + WT_OFF);
    _Float16* hbuf = (_Float16*)(smem + HB_OFF);
    float4*   psum = (float4*)(smem + PS_OFF);
    float*    esh  = (float*)(smem + ESH_OFF);

    f16x2 wr[128];
    const float4* Wh4 = (const float4*)W_hh;
    #pragma unroll
    for (int g = 0; g < 4; ++g) {
        const int r = j + 256 * g;
        #pragma unroll
        for (int c = 0; c < REGC; ++c) {
            const int f4i = r * 64 + (88 * s + 8 * c) / 4;
            float4 a = Wh4[f4i];
            float4 d = Wh4[f4i + 1];
            wr[g * 32 + c * 4 + 0] = f16x2{(_Float16)a.x, (_Float16)a.y};
            wr[g * 32 + c * 4 + 1] = f16x2{(_Float16)a.z, (_Float16)a.w};
            wr[g * 32 + c * 4 + 2] = f16x2{(_Float16)d.x, (_Float16)d.y};
            wr[g * 32 + c * 4 + 3] = f16x2{(_Float16)d.z, (_Float16)d.w};
        }
        #pragma unroll
        for (int c = 0; c < LDSC; ++c) {
            const int k0 = 88 * s + 8 * (REGC + c);
            union { f16x8 v; f16x2 p[4]; } u;
            if (k0 < 256) {
                float4 a = Wh4[r * 64 + k0 / 4];
                float4 d = Wh4[r * 64 + k0 / 4 + 1];
                u.p[0] = f16x2{(_Float16)a.x, (_Float16)a.y};
                u.p[1] = f16x2{(_Float16)a.z, (_Float16)a.w};
                u.p[2] = f16x2{(_Float16)d.x, (_Float16)d.y};
                u.p[3] = f16x2{(_Float16)d.z, (_Float16)d.w};
            } else {
                u.p[0] = f16x2{0, 0}; u.p[1] = f16x2{0, 0};
                u.p[2] = f16x2{0, 0}; u.p[3] = f16x2{0, 0};
            }
            wt8[(g * LDSC + c) * NTHR + tid] = u.v;
        }
    }

    float bias[4] = {0.f, 0.f, 0.f, 0.f};
    if (s == 0) {
        #pragma unroll
        for (int g = 0; g < 4; ++g)
            bias[g] = b_ih[j + g * 256] + b_hh[j + g * 256];
    }

    float cst = 0.f, hval = 0.f;
    if (s == 0) {
        cst  = c0[b * HID + j];
        hval = h0[b * HID + j];
        hbuf[j] = (_Float16)hval;
    }
    if (tid < 8) {
        hbuf[256 + tid]        = (_Float16)0.f;
        hbuf[HPAD + 256 + tid] = (_Float16)0.f;
    }

    for (int t = 0; t < T_STEPS; ++t) {
        __syncthreads();
        const f16x8* hb = (const f16x8*)(hbuf + (t & 1) * HPAD);

        float acc[4] = {0.f, 0.f, 0.f, 0.f};
        if (s != 0) {
            const float4* Wi4 = (const float4*)W_ih;
            const float4* xv4 = (const float4*)(x + ((size_t)t * BATCH + b) * IN)
                                + (s - 1) * 8;
            #pragma unroll
            for (int q = 0; q < 8; ++q) {
                float4 xv = xv4[q];
                #pragma unroll
                for (int g = 0; g < 4; ++g) {
                    float4 wv = Wi4[(j + 256 * g) * 16 + (s - 1) * 8 + q];
                    acc[g] += wv.x * xv.x + wv.y * xv.y + wv.z * xv.z + wv.w * xv.w;
                }
            }
        }
        #pragma unroll
        for (int c = 0; c < REGC; ++c) {
            union { f16x8 v; f16x2 p[4]; } hu;
            hu.v = hb[s * KC + c];
            #pragma unroll
            for (int uu = 0; uu < 4; ++uu) {
                #pragma unroll
                for (int g = 0; g < 4; ++g)
                    acc[g] = fdot2(wr[g * 32 + c * 4 + uu], hu.p[uu], acc[g]);
            }
        }
        #pragma unroll
        for (int c = 0; c < LDSC; ++c) {
            union { f16x8 v; f16x2 p[4]; } hu;
            hu.v = hb[s * KC + REGC + c];
            #pragma unroll
            for (int g = 0; g < 4; ++g) {
                union { f16x8 v; f16x2 p[4]; } wu;
                wu.v = wt8[(g * LDSC + c) * NTHR + tid];
                #pragma unroll
                for (int uu = 0; uu < 4; ++uu)
                    acc[g] = fdot2(wu.p[uu], hu.p[uu], acc[g]);
            }
        }
        if (s != 0)
            psum[(s - 1) * 256 + j] = float4{acc[0], acc[1], acc[2], acc[3]};
        __syncthreads();
        if (s == 0) {
            float4 p1 = psum[j];
            float4 p2 = psum[256 + j];
            float gi = sigf(acc[0] + p1.x + p2.x + bias[0]);
            float gf = sigf(acc[1] + p1.y + p2.y + bias[1]);
            float gg = tanh_fast(acc[2] + p1.z + p2.z + bias[2]);
            float go = sigf(acc[3] + p1.w + p2.w + bias[3]);
            cst  = gf * cst + gi * gg;
            hval = go * tanh_fast(cst);
            hbuf[((t + 1) & 1) * HPAD + j] = (_Float16)hval;
        }
    }

    if (s == 0) esh[j] = hval * W_lin[j];
    __syncthreads();
    if (tid == 0) {
        float z = b_lin[0];
        for (int n = 0; n < 256; ++n) z += esh[n];
        out[b] = sigf(z);
    }
}

extern "C" void kernel_launch(void* const* d_in, const int* in_sizes, int n_in,
                              void* d_out, int out_size, void* d_ws, size_t ws_size,
                              hipStream_t stream) {
    const float* x     = (const float*)d_in[0];
    const float* W_ih  = (const float*)d_in[1];
    const float* W_hh  = (const float*)d_in[2];
    const float* b_ih  = (const float*)d_in[3];
    const float* b_hh  = (const float*)d_in[4];
    const float* W_lin = (const float*)d_in[5];
    const float* b_lin = (const float*)d_in[6];
    const float* h0    = (const float*)d_in[7];
    const float* c0    = (const float*)d_in[8];
    float* out = (float*)d_out;

    const size_t need = (size_t)T_STEPS * BATCH * G4 * sizeof(_Float16); // 128 MB
    if (ws_size >= need) {
        _Float16* xg = (_Float16*)d_ws;
        xg_precompute<<<dim3(BATCH, 32), 256, 0, stream>>>(x, W_ih, b_ih, b_hh, xg);
        lstm_mfma<<<dim3(BATCH), 1024, 0, stream>>>(
            W_hh, W_lin, b_lin, h0, c0, xg, out);
    } else {
        (void)hipFuncSetAttribute((const void*)lstm_fb,
                                  hipFuncAttributeMaxDynamicSharedMemorySize,
                                  SMEM_BYTES);
        lstm_fb<<<dim3(BATCH), NTHR, SMEM_BYTES, stream>>>(
            x, W_ih, W_hh, b_ih, b_hh, W_lin, b_lin, h0, c0, out);
    }
}

// Round 15
// 3159.616 us; speedup vs baseline: 1.0792x; 1.0792x over previous
//
#include <hip/hip_runtime.h>
#include <hip/hip_bf16.h>

// LSTM T=4096, B=16, I=64, H=256 (4H=1024 gate rows), O=1.
//
// R15 = R13 RESTORED (best verified: 2985us, absmax 2e-3).
// R14 (independent accumulators) regressed 2985->3224: allocator folded the
// 16 accumulators (VGPR stayed 64) and added init/add overhead; MfmaUtil
// DROPPED. Cross-wave interleave already packs the MFMA issue pipe.
// R12 (distributed epilogue) regressed via added LDS roundtrip latency.
// => step = 1306-cyc i8-MFMA issue floor + ~440 cyc irreducible serial
// handoff (barrier + ds_read h + MFMA drain + activation->c->h chain).
//
// Structure (verified R10/R11/R13): 16 WGs x 1024 thr (16 waves, 4/SIMD).
// Wave w, lane col=l&15 owns unit u=w*16+col; gate rows g*256+u. Weights:
// 4x4 i32x4 = 64 VGPRs of MFMA operands (allocator-proof). Per-gate-row
// symmetric int8 quant, preact = (rowmax/127^2)*acc_int + xg, int32 exact.
// h int8 in LDS identity layout (4x b128 broadcast, 0 conflicts), double-
// buffered; magic-number RNE h-quantize; ONE barrier/step; all-lane
// redundant epilogue; xg fp16 [t][b][u*4+g] prefetched via pointer.

typedef _Float16 f16x2 __attribute__((ext_vector_type(2)));
typedef _Float16 f16x4 __attribute__((ext_vector_type(4)));
typedef int      i32x4 __attribute__((ext_vector_type(4)));

#define T_STEPS 4096
#define BATCH   16
#define IN      64
#define HID     256
#define G4      1024

__device__ __forceinline__ float fdot2(f16x2 a, f16x2 b, float c) {
#if __has_builtin(__builtin_amdgcn_fdot2)
    return __builtin_amdgcn_fdot2(a, b, c, false);
#else
    return c + (float)a.x * (float)b.x + (float)a.y * (float)b.y;
#endif
}

__device__ __forceinline__ float fast_rcp(float x) {
#if __has_builtin(__builtin_amdgcn_rcpf)
    return __builtin_amdgcn_rcpf(x);
#else
    return 1.0f / x;
#endif
}

__device__ __forceinline__ float sigf(float x) {
    return fast_rcp(1.0f + __expf(-x));
}
__device__ __forceinline__ float tanh_fast(float x) {
    return 2.0f * sigf(2.0f * x) - 1.0f;
}

// ---------------- Kernel A: x_gates precompute (transposed store) ----------
__global__ __launch_bounds__(256) void xg_precompute(
    const float* __restrict__ x, const float* __restrict__ W_ih,
    const float* __restrict__ b_ih, const float* __restrict__ b_hh,
    _Float16* __restrict__ xg)
{
    const int b   = blockIdx.x;
    const int t0  = blockIdx.y * 128;
    const int tid = threadIdx.x;

    __shared__ __align__(16) f16x2 xs2[IN / 2];

    f16x2 wih[4][32];
    float bias[4];
    const float2* W2 = (const float2*)W_ih;
    #pragma unroll
    for (int g = 0; g < 4; ++g) {
        const int r = tid + g * 256;
        #pragma unroll
        for (int m = 0; m < 32; ++m) {
            float2 v = W2[r * 32 + m];
            wih[g][m] = f16x2{(_Float16)v.x, (_Float16)v.y};
        }
        bias[g] = b_ih[r] + b_hh[r];
    }

    for (int tt = 0; tt < 128; ++tt) {
        const int t = t0 + tt;
        if (tid < 32) {
            float2 v = ((const float2*)x)[(t * BATCH + b) * 32 + tid];
            xs2[tid] = f16x2{(_Float16)v.x, (_Float16)v.y};
        }
        __syncthreads();
        float acc[4] = {bias[0], bias[1], bias[2], bias[3]};
        #pragma unroll
        for (int m = 0; m < 32; ++m) {
            f16x2 xv = xs2[m];
            #pragma unroll
            for (int g = 0; g < 4; ++g) acc[g] = fdot2(wih[g][m], xv, acc[g]);
        }
        f16x4 v4 = f16x4{(_Float16)acc[0], (_Float16)acc[1],
                         (_Float16)acc[2], (_Float16)acc[3]};
        ((f16x4*)xg)[(t * BATCH + b) * 256 + tid] = v4;
        __syncthreads();
    }
}

// ---------------- Kernel B: i8-MFMA persistent recurrence ----------------
__global__ __launch_bounds__(1024, 4) void lstm_mfma(
    const float* __restrict__ W_hh,  const float* __restrict__ W_lin,
    const float* __restrict__ b_lin, const float* __restrict__ h0,
    const float* __restrict__ c0,    const _Float16* __restrict__ xg,
    float* __restrict__ out)
{
    const int b   = blockIdx.x;
    const int tid = threadIdx.x;
    const int w   = tid >> 6;     // wave 0..15
    const int l   = tid & 63;     // lane
    const int col = l & 15;       // MFMA col for this lane
    const int g4  = l >> 4;       // k lane-group 0..3

    __shared__ __align__(16) signed char hs[2][256];  // h int8, identity layout
    __shared__ float esh[256];

    const int u = w * 16 + col;   // unit this lane covers

    // ---- one-time: per-gate-row max, then W_hh -> int8 B-fragments ----
    const float4* Wh4 = (const float4*)W_hh;          // row stride 64 float4
    float qs[4], ksc[4];
    {
        float rm[4];
        #pragma unroll
        for (int g = 0; g < 4; ++g) {
            const int row = g * 256 + u;
            float m = 0.0f;
            #pragma unroll
            for (int c = 0; c < 4; ++c) {
                #pragma unroll
                for (int d = 0; d < 4; ++d) {
                    float4 v = Wh4[row * 64 + 16 * c + 4 * g4 + d];
                    m = fmaxf(m, fmaxf(fmaxf(fabsf(v.x), fabsf(v.y)),
                                       fmaxf(fabsf(v.z), fabsf(v.w))));
                }
            }
            rm[g] = m;
        }
        #pragma unroll
        for (int g = 0; g < 4; ++g) {                  // max across g4 groups
            rm[g] = fmaxf(rm[g], __shfl_xor(rm[g], 16, 64));
            rm[g] = fmaxf(rm[g], __shfl_xor(rm[g], 32, 64));
            rm[g] = fmaxf(rm[g], 1e-20f);
            qs[g]  = 127.0f / rm[g];
            ksc[g] = rm[g] * (1.0f / 16129.0f);        // rm/127^2
        }
    }
    i32x4 wf[4][4];
    #pragma unroll
    for (int g = 0; g < 4; ++g) {
        const int row = g * 256 + u;
        #pragma unroll
        for (int c = 0; c < 4; ++c) {
            union { int i[4]; i32x4 v; } uu;
            #pragma unroll
            for (int d = 0; d < 4; ++d) {
                float4 v = Wh4[row * 64 + 16 * c + 4 * g4 + d];
                int b0 = (int)rintf(v.x * qs[g]) & 255;
                int b1 = (int)rintf(v.y * qs[g]) & 255;
                int b2 = (int)rintf(v.z * qs[g]) & 255;
                int b3 = (int)rintf(v.w * qs[g]) & 255;
                uu.i[d] = b0 | (b1 << 8) | (b2 << 16) | (b3 << 24);
            }
            wf[g][c] = uu.v;
        }
    }

    // ---- state (lane l<16 owns unit u's write) ----
    const float MAGIC = 12582912.0f;                   // 1.5 * 2^23
    float cst  = c0[b * HID + u];
    float hval = h0[b * HID + u];
    if (l < 16) {
        union { float f; int i; } m0;
        m0.f = __builtin_fmaf(hval, 127.0f, MAGIC);    // RNE int in low bits
        hs[0][u] = (signed char)(m0.i & 0xff);
    }

    union XU { uint2 i; f16x4 h; };
    const uint2* xp = (const uint2*)xg + b * 256 + u;  // stride BATCH*256/step
    XU xc; xc.i = *xp;
    xp += BATCH * 256;

    for (int t = 0; t < T_STEPS; ++t) {
        __syncthreads();   // h(t) in hs[t&1] visible

        // A fragments: chunk c = bytes [64c + 16*g4, +16) -> 4x b128 broadcast
        const uint4* hsv = (const uint4*)(&hs[t & 1][0]);
        union AU { uint4 q; i32x4 v; } a0, a1, a2, a3;
        a0.q = hsv[g4];
        a1.q = hsv[4 + g4];
        a2.q = hsv[8 + g4];
        a3.q = hsv[12 + g4];

        // prefetch next step's x-gates (pointer-incremented)
        XU xn;
        if (t + 1 < T_STEPS) { xn.i = *xp; xp += BATCH * 256; }
        else                 { xn = xc; }

        i32x4 acc0 = {0, 0, 0, 0};
        i32x4 acc1 = {0, 0, 0, 0};
        i32x4 acc2 = {0, 0, 0, 0};
        i32x4 acc3 = {0, 0, 0, 0};

        acc0 = __builtin_amdgcn_mfma_i32_16x16x64_i8(a0.v, wf[0][0], acc0, 0, 0, 0);
        acc1 = __builtin_amdgcn_mfma_i32_16x16x64_i8(a0.v, wf[1][0], acc1, 0, 0, 0);
        acc2 = __builtin_amdgcn_mfma_i32_16x16x64_i8(a0.v, wf[2][0], acc2, 0, 0, 0);
        acc3 = __builtin_amdgcn_mfma_i32_16x16x64_i8(a0.v, wf[3][0], acc3, 0, 0, 0);
        acc0 = __builtin_amdgcn_mfma_i32_16x16x64_i8(a1.v, wf[0][1], acc0, 0, 0, 0);
        acc1 = __builtin_amdgcn_mfma_i32_16x16x64_i8(a1.v, wf[1][1], acc1, 0, 0, 0);
        acc2 = __builtin_amdgcn_mfma_i32_16x16x64_i8(a1.v, wf[2][1], acc2, 0, 0, 0);
        acc3 = __builtin_amdgcn_mfma_i32_16x16x64_i8(a1.v, wf[3][1], acc3, 0, 0, 0);
        acc0 = __builtin_amdgcn_mfma_i32_16x16x64_i8(a2.v, wf[0][2], acc0, 0, 0, 0);
        acc1 = __builtin_amdgcn_mfma_i32_16x16x64_i8(a2.v, wf[1][2], acc1, 0, 0, 0);
        acc2 = __builtin_amdgcn_mfma_i32_16x16x64_i8(a2.v, wf[2][2], acc2, 0, 0, 0);
        acc3 = __builtin_amdgcn_mfma_i32_16x16x64_i8(a2.v, wf[3][2], acc3, 0, 0, 0);
        acc0 = __builtin_amdgcn_mfma_i32_16x16x64_i8(a3.v, wf[0][3], acc0, 0, 0, 0);
        acc1 = __builtin_amdgcn_mfma_i32_16x16x64_i8(a3.v, wf[1][3], acc1, 0, 0, 0);
        acc2 = __builtin_amdgcn_mfma_i32_16x16x64_i8(a3.v, wf[2][3], acc2, 0, 0, 0);
        acc3 = __builtin_amdgcn_mfma_i32_16x16x64_i8(a3.v, wf[3][3], acc3, 0, 0, 0);

        // D rows identical -> acc reg0 of ANY lane = int preact(col).
        // All-lane redundant epilogue (issue hides under MFMA shadow).
        float gi = sigf((float)acc0[0] * ksc[0] + (float)xc.h[0]);
        float gf = sigf((float)acc1[0] * ksc[1] + (float)xc.h[1]);
        float gg = tanh_fast((float)acc2[0] * ksc[2] + (float)xc.h[2]);
        float go = sigf((float)acc3[0] * ksc[3] + (float)xc.h[3]);
        cst  = gf * cst + gi * gg;
        hval = go * tanh_fast(cst);
        if (l < 16) {
            union { float f; int i; } mg;
            mg.f = __builtin_fmaf(hval, 127.0f, MAGIC);   // RNE, low byte = i8
            hs[(t + 1) & 1][u] = (signed char)(mg.i & 0xff);
        }
        xc = xn;
    }

    // ---- epilogue: y[b] = sigmoid(h . W_lin + b_lin) ----
    if (l < 16) esh[u] = hval * W_lin[u];
    __syncthreads();
    if (tid == 0) {
        float z = b_lin[0];
        for (int n = 0; n < 256; ++n) z += esh[n];
        out[b] = sigf(z);
    }
}

// ---------------- Fallback (ws too small): R6 dot2 kernel, x streamed ------
#define NTHR 768
#define KC   11
#define REGC 8
#define LDSC 3
#define HPAD 264
#define WT_OFF   0
#define HB_OFF   147456
#define PS_OFF   148512
#define ESH_OFF  156704
#define SMEM_BYTES 157728
typedef _Float16 f16x8 __attribute__((ext_vector_type(8)));

__global__ __launch_bounds__(NTHR, 3) void lstm_fb(
    const float* __restrict__ x,     const float* __restrict__ W_ih,
    const float* __restrict__ W_hh,  const float* __restrict__ b_ih,
    const float* __restrict__ b_hh,  const float* __restrict__ W_lin,
    const float* __restrict__ b_lin, const float* __restrict__ h0,
    const float* __restrict__ c0,    float* __restrict__ out)
{
    const int b   = blockIdx.x;
    const int tid = threadIdx.x;
    const int j   = tid & 255;
    const int s   = tid >> 8;

    extern __shared__ __align__(16) char smem[];
    f16x8*    wt8  = (f16x8*)(smem + WT_OFF);
    _Float16* hbuf = (_Float16*)(smem + HB_OFF);
    float4*   psum = (float4*)(smem + PS_OFF);
    float*    esh  = (float*)(smem + ESH_OFF);

    f16x2 wr[128];
    const float4* Wh4 = (const float4*)W_hh;
    #pragma unroll
    for (int g = 0; g < 4; ++g) {
        const int r = j + 256 * g;
        #pragma unroll
        for (int c = 0; c < REGC; ++c) {
            const int f4i = r * 64 + (88 * s + 8 * c) / 4;
            float4 a = Wh4[f4i];
            float4 d = Wh4[f4i + 1];
            wr[g * 32 + c * 4 + 0] = f16x2{(_Float16)a.x, (_Float16)a.y};
            wr[g * 32 + c * 4 + 1] = f16x2{(_Float16)a.z, (_Float16)a.w};
            wr[g * 32 + c * 4 + 2] = f16x2{(_Float16)d.x, (_Float16)d.y};
            wr[g * 32 + c * 4 + 3] = f16x2{(_Float16)d.z, (_Float16)d.w};
        }
        #pragma unroll
        for (int c = 0; c < LDSC; ++c) {
            const int k0 = 88 * s + 8 * (REGC + c);
            union { f16x8 v; f16x2 p[4]; } u;
            if (k0 < 256) {
                float4 a = Wh4[r * 64 + k0 / 4];
                float4 d = Wh4[r * 64 + k0 / 4 + 1];
                u.p[0] = f16x2{(_Float16)a.x, (_Float16)a.y};
                u.p[1] = f16x2{(_Float16)a.z, (_Float16)a.w};
                u.p[2] = f16x2{(_Float16)d.x, (_Float16)d.y};
                u.p[3] = f16x2{(_Float16)d.z, (_Float16)d.w};
            } else {
                u.p[0] = f16x2{0, 0}; u.p[1] = f16x2{0, 0};
                u.p[2] = f16x2{0, 0}; u.p[3] = f16x2{0, 0};
            }
            wt8[(g * LDSC + c) * NTHR + tid] = u.v;
        }
    }

    float bias[4] = {0.f, 0.f, 0.f, 0.f};
    if (s == 0) {
        #pragma unroll
        for (int g = 0; g < 4; ++g)
            bias[g] = b_ih[j + g * 256] + b_hh[j + g * 256];
    }

    float cst = 0.f, hval = 0.f;
    if (s == 0) {
        cst  = c0[b * HID + j];
        hval = h0[b * HID + j];
        hbuf[j] = (_Float16)hval;
    }
    if (tid < 8) {
        hbuf[256 + tid]        = (_Float16)0.f;
        hbuf[HPAD + 256 + tid] = (_Float16)0.f;
    }

    for (int t = 0; t < T_STEPS; ++t) {
        __syncthreads();
        const f16x8* hb = (const f16x8*)(hbuf + (t & 1) * HPAD);

        float acc[4] = {0.f, 0.f, 0.f, 0.f};
        if (s != 0) {
            const float4* Wi4 = (const float4*)W_ih;
            const float4* xv4 = (const float4*)(x + ((size_t)t * BATCH + b) * IN)
                                + (s - 1) * 8;
            #pragma unroll
            for (int q = 0; q < 8; ++q) {
                float4 xv = xv4[q];
                #pragma unroll
                for (int g = 0; g < 4; ++g) {
                    float4 wv = Wi4[(j + 256 * g) * 16 + (s - 1) * 8 + q];
                    acc[g] += wv.x * xv.x + wv.y * xv.y + wv.z * xv.z + wv.w * xv.w;
                }
            }
        }
        #pragma unroll
        for (int c = 0; c < REGC; ++c) {
            union { f16x8 v; f16x2 p[4]; } hu;
            hu.v = hb[s * KC + c];
            #pragma unroll
            for (int uu = 0; uu < 4; ++uu) {
                #pragma unroll
                for (int g = 0; g < 4; ++g)
                    acc[g] = fdot2(wr[g * 32 + c * 4 + uu], hu.p[uu], acc[g]);
            }
        }
        #pragma unroll
        for (int c = 0; c < LDSC; ++c) {
            union { f16x8 v; f16x2 p[4]; } hu;
            hu.v = hb[s * KC + REGC + c];
            #pragma unroll
            for (int g = 0; g < 4; ++g) {
                union { f16x8 v; f16x2 p[4]; } wu;
                wu.v = wt8[(g * LDSC + c) * NTHR + tid];
                #pragma unroll
                for (int uu = 0; uu < 4; ++uu)
                    acc[g] = fdot2(wu.p[uu], hu.p[uu], acc[g]);
            }
        }
        if (s != 0)
            psum[(s - 1) * 256 + j] = float4{acc[0], acc[1], acc[2], acc[3]};
        __syncthreads();
        if (s == 0) {
            float4 p1 = psum[j];
            float4 p2 = psum[256 + j];
            float gi = sigf(acc[0] + p1.x + p2.x + bias[0]);
            float gf = sigf(acc[1] + p1.y + p2.y + bias[1]);
            float gg = tanh_fast(acc[2] + p1.z + p2.z + bias[2]);
            float go = sigf(acc[3] + p1.w + p2.w + bias[3]);
            cst  = gf * cst + gi * gg;
            hval = go * tanh_fast(cst);
            hbuf[((t + 1) & 1) * HPAD + j] = (_Float16)hval;
        }
    }

    if (s == 0) esh[j] = hval * W_lin[j];
    __syncthreads();
    if (tid == 0) {
        float z = b_lin[0];
        for (int n = 0; n < 256; ++n) z += esh[n];
        out[b] = sigf(z);
    }
}

extern "C" void kernel_launch(void* const* d_in, const int* in_sizes, int n_in,
                              void* d_out, int out_size, void* d_ws, size_t ws_size,
                              hipStream_t stream) {
    const float* x     = (const float*)d_in[0];
    const float* W_ih  = (const float*)d_in[1];
    const float* W_hh  = (const float*)d_in[2];
    const float* b_ih  = (const float*)d_in[3];
    const float* b_hh  = (const float*)d_in[4];
    const float* W_lin = (const float*)d_in[5];
    const float* b_lin = (const float*)d_in[6];
    const float* h0    = (const float*)d_in[7];
    const float* c0    = (const float*)d_in[8];
    float* out = (float*)d_out;

    const size_t need = (size_t)T_STEPS * BATCH * G4 * sizeof(_Float16); // 128 MB
    if (ws_size >= need) {
        _Float16* xg = (_Float16*)d_ws;
        xg_precompute<<<dim3(BATCH, 32), 256, 0, stream>>>(x, W_ih, b_ih, b_hh, xg);
        lstm_mfma<<<dim3(BATCH), 1024, 0, stream>>>(
            W_hh, W_lin, b_lin, h0, c0, xg, out);
    } else {
        (void)hipFuncSetAttribute((const void*)lstm_fb,
                                  hipFuncAttributeMaxDynamicSharedMemorySize,
                                  SMEM_BYTES);
        lstm_fb<<<dim3(BATCH), NTHR, SMEM_BYTES, stream>>>(
            x, W_ih, W_hh, b_ih, b_hh, W_lin, b_lin, h0, c0, out);
    }
}